// Round 13
// baseline (106.670 us; speedup 1.0000x reference)
//
#include <hip/hip_runtime.h>
#include <stdint.h>

#define NAG   8192
#define NK    4096
#define BLOCK 256
#define ROWS  4
#define CHUNK 128
#define NCK   (NAG / CHUNK)   // 64
#define NCG   (NK  / CHUNK)   // 32
#define AGB   (BLOCK * ROWS)  // 1024
#define NBLK  (NAG / AGB)     // 8 agent blocks
#define NBIN  256
#define BINW  0.0390625f      // 10/256, domain [-5,5]
#define RK    0.38f           // exp2 cutoff ~2^-41 for KDE
#define RG    0.59f           // exp2 cutoff ~2^-41 for GMM (lw<=0 only helps)

#define SK_SCALE 16.98643615f
#define SG_SCALE 10.87131904f
#define SC_B   (23.5482041f)
#define SC_C   (50569.375f)
#define SC_F   (3355.4432f)

typedef float f32x2 __attribute__((ext_vector_type(2)));

__device__ __forceinline__ f32x2 pk_add(f32x2 a, f32x2 b) {
  f32x2 d; asm("v_pk_add_f32 %0, %1, %2" : "=v"(d) : "v"(a), "v"(b)); return d;
}
__device__ __forceinline__ f32x2 pk_mul(f32x2 a, f32x2 b) {
  f32x2 d; asm("v_pk_mul_f32 %0, %1, %2" : "=v"(d) : "v"(a), "v"(b)); return d;
}
__device__ __forceinline__ f32x2 pk_fma(f32x2 a, f32x2 b, f32x2 c) {
  f32x2 d; asm("v_pk_fma_f32 %0, %1, %2, %3" : "=v"(d) : "v"(a), "v"(b), "v"(c));
  return d;
}
__device__ __forceinline__ f32x2 bcast(float a) { return (f32x2){a, a}; }

// K0: counting-sort agents and means by x-bin; emit sorted arrays + slab bounds.
__global__ __launch_bounds__(1024) void wm_sort_kernel(
    const float*  __restrict__ t,  const float2* __restrict__ X,
    const float2* __restrict__ m0, const float2* __restrict__ mv,
    const float*  __restrict__ w,
    float2* __restrict__ sX,  int*   __restrict__ sidx,
    float4* __restrict__ sMP, float* __restrict__ sLW,
    float2* __restrict__ cbK, float2* __restrict__ cbG, float2* __restrict__ bbA) {
  __shared__ int hist[NBIN];
  __shared__ int ofs[NBIN];
  __shared__ unsigned char sbin[NAG];
  const int tid = threadIdx.x;

  // ---- agents ----
  if (tid < NBIN) hist[tid] = 0;
  __syncthreads();
  int ab[8]; float2 ax[8];
#pragma unroll
  for (int k = 0; k < 8; ++k) {
    const int i = tid + k * 1024;
    const float2 v = X[i];
    int b = (int)((v.x + 5.0f) * (1.0f / BINW));
    b = b < 0 ? 0 : (b > NBIN - 1 ? NBIN - 1 : b);
    ab[k] = b; ax[k] = v;
    atomicAdd(&hist[b], 1);
  }
  __syncthreads();
  if (tid == 0) { int run = 0; for (int b = 0; b < NBIN; ++b) { ofs[b] = run; run += hist[b]; } }
  __syncthreads();
#pragma unroll
  for (int k = 0; k < 8; ++k) {
    const int pos = atomicAdd(&ofs[ab[k]], 1);
    sX[pos]   = ax[k];
    sidx[pos] = tid + k * 1024;
    sbin[pos] = (unsigned char)ab[k];
  }
  __syncthreads();
  if (tid < NCK)
    cbK[tid] = make_float2(sbin[tid * CHUNK] * BINW - 5.0f,
                           (sbin[tid * CHUNK + CHUNK - 1] + 1) * BINW - 5.0f);
  if (tid < NBLK)
    bbA[tid] = make_float2(sbin[tid * AGB] * BINW - 5.0f,
                           (sbin[tid * AGB + AGB - 1] + 1) * BINW - 5.0f);
  __syncthreads();

  // ---- means (t-dependent, re-binned every call) ----
  if (tid < NBIN) hist[tid] = 0;
  __syncthreads();
  const float tt = t[0];
  int mb[4]; float4 mp[4]; float ml[4];
#pragma unroll
  for (int k = 0; k < 4; ++k) {
    const int i = tid + k * 1024;
    const float2 a = m0[i], d = mv[i];
    const float mx = __builtin_fmaf(d.x, tt, a.x);
    const float my = __builtin_fmaf(d.y, tt, a.y);
    int b = (int)((mx + 5.0f) * (1.0f / BINW));
    b = b < 0 ? 0 : (b > NBIN - 1 ? NBIN - 1 : b);
    mb[k] = b;
    mp[k] = make_float4(-SG_SCALE * mx, -SG_SCALE * my, d.x, d.y);
    ml[k] = __log2f(w[i]);
    atomicAdd(&hist[b], 1);
  }
  __syncthreads();
  if (tid == 0) { int run = 0; for (int b = 0; b < NBIN; ++b) { ofs[b] = run; run += hist[b]; } }
  __syncthreads();
#pragma unroll
  for (int k = 0; k < 4; ++k) {
    const int pos = atomicAdd(&ofs[mb[k]], 1);
    sMP[pos]  = mp[k];
    sLW[pos]  = ml[k];
    sbin[pos] = (unsigned char)mb[k];
  }
  __syncthreads();
  if (tid < NCG)
    cbG[tid] = make_float2(sbin[tid * CHUNK] * BINW - 5.0f,
                           (sbin[tid * CHUNK + CHUNK - 1] + 1) * BINW - 5.0f);
}

// K1: pair interactions in sorted space with block-uniform slab skip.
__global__ __launch_bounds__(BLOCK) void wm_pair_kernel(
    const float2* __restrict__ sX,
    const float4* __restrict__ sMP, const float* __restrict__ sLW,
    const float2* __restrict__ cbK, const float2* __restrict__ cbG,
    const float2* __restrict__ bbA,
    float4* __restrict__ pK, float4* __restrict__ pG) {
  __shared__ float4 sGP[CHUNK];
  __shared__ float  sWL[CHUNK];

  const int iBase = blockIdx.x * AGB + threadIdx.x;
  const int c = blockIdx.y;
  const float2 bb = bbA[blockIdx.x];

  if (c < NCK) {
    // ---------------- KDE chunk ----------------
    const float2 cb = cbK[c];
    if (cb.x > bb.y + RK || cb.y < bb.x - RK) {   // block-uniform skip
#pragma unroll
      for (int r = 0; r < ROWS; ++r)
        pK[c * NAG + iBase + r * BLOCK] = make_float4(0.f, 0.f, 0.f, 0.f);
      return;
    }
    f32x2* sNP = reinterpret_cast<f32x2*>(sGP);
    const int base = c * CHUNK;
    if (threadIdx.x < CHUNK) {
      const float2 xj = sX[base + threadIdx.x];
      sNP[threadIdx.x] = (f32x2){-SK_SCALE * xj.x, -SK_SCALE * xj.y};
    }
    __syncthreads();

    f32x2 xi[ROWS];
#pragma unroll
    for (int r = 0; r < ROWS; ++r) {
      const float2 v = sX[iBase + r * BLOCK];
      xi[r] = (f32x2){SK_SCALE * v.x, SK_SCALE * v.y};
    }
    float A[ROWS]; f32x2 B[ROWS];
#pragma unroll
    for (int r = 0; r < ROWS; ++r) { A[r] = 0.f; B[r] = (f32x2){0.f, 0.f}; }

#pragma unroll 4
    for (int j = 0; j < CHUNK; ++j) {
      const f32x2 p = sNP[j];
#pragma unroll
      for (int r = 0; r < ROWS; ++r) {
        const f32x2 pd = pk_add(xi[r], p);
        const f32x2 sq = pk_mul(pd, pd);
        const float e  = __builtin_amdgcn_exp2f(-(sq.x + sq.y));
        A[r] += e;
        B[r] = pk_fma(bcast(e), pd, B[r]);
      }
    }
#pragma unroll
    for (int r = 0; r < ROWS; ++r)
      pK[c * NAG + iBase + r * BLOCK] = make_float4(A[r], B[r].x, B[r].y, 0.f);
  } else {
    // ---------------- GMM chunk ----------------
    const int cg = c - NCK;
    const float2 cb = cbG[cg];
    if (cb.x > bb.y + RG || cb.y < bb.x - RG) {
#pragma unroll
      for (int r = 0; r < ROWS; ++r)
        pG[cg * NAG + iBase + r * BLOCK] = make_float4(0.f, 0.f, 0.f, 0.f);
      return;
    }
    const int base = cg * CHUNK;
    if (threadIdx.x < CHUNK) {
      sGP[threadIdx.x] = sMP[base + threadIdx.x];   // {-sG*m, mv} presorted
      sWL[threadIdx.x] = sLW[base + threadIdx.x];   // log2(w)
    }
    __syncthreads();

    f32x2 xg[ROWS];
#pragma unroll
    for (int r = 0; r < ROWS; ++r) {
      const float2 v = sX[iBase + r * BLOCK];
      xg[r] = (f32x2){SG_SCALE * v.x, SG_SCALE * v.y};
    }
    f32x2 C[ROWS], F[ROWS];
#pragma unroll
    for (int r = 0; r < ROWS; ++r) { C[r] = (f32x2){0.f, 0.f}; F[r] = (f32x2){0.f, 0.f}; }

#pragma unroll 4
    for (int j = 0; j < CHUNK; ++j) {
      const float4 p = sGP[j];
      const float lw = sWL[j];
      const f32x2 nm = (f32x2){p.x, p.y};
      const f32x2 mj = (f32x2){p.z, p.w};
#pragma unroll
      for (int r = 0; r < ROWS; ++r) {
        const f32x2 pd = pk_add(xg[r], nm);
        const f32x2 sq = pk_mul(pd, pd);
        const float gf = __builtin_amdgcn_exp2f(lw - sq.x - sq.y);
        const f32x2 gd = bcast(gf);
        C[r] = pk_fma(gd, pd, C[r]);
        F[r] = pk_fma(gd, mj, F[r]);
      }
    }
#pragma unroll
    for (int r = 0; r < ROWS; ++r)
      pG[cg * NAG + iBase + r * BLOCK] = make_float4(C[r].x, C[r].y, F[r].x, F[r].y);
  }
}

// K2: reduce chunk planes (sorted space) + finalize + scatter to original order.
__global__ __launch_bounds__(64) void wm_final_kernel(
    const float4* __restrict__ pK, const float4* __restrict__ pG,
    const int* __restrict__ sidx, float2* __restrict__ out) {
  const int i = blockIdx.x * 64 + threadIdx.x;
  float A = 0.f, Bx = 0.f, By = 0.f;
#pragma unroll 8
  for (int c = 0; c < NCK; ++c) {
    const float4 v = pK[c * NAG + i];
    A += v.x; Bx += v.y; By += v.z;
  }
  float Cx = 0.f, Cy = 0.f, Fx = 0.f, Fy = 0.f;
#pragma unroll 8
  for (int c = 0; c < NCG; ++c) {
    const float4 v = pG[c * NAG + i];
    Cx += v.x; Cy += v.y; Fx += v.z; Fy += v.w;
  }
  const float invA = 1.0f / A;   // self term e=1 never skipped (d=0)
  const float ox = (SC_B * Bx - SC_C * Cx + SC_F * Fx) * invA;
  const float oy = (SC_B * By - SC_C * Cy + SC_F * Fy) * invA;
  out[sidx[i]] = make_float2(ox, oy);
}

extern "C" void kernel_launch(void* const* d_in, const int* in_sizes, int n_in,
                              void* d_out, int out_size, void* d_ws, size_t ws_size,
                              hipStream_t stream) {
  const float*  t  = (const float*)d_in[0];
  const float2* X  = (const float2*)d_in[1];
  const float2* m0 = (const float2*)d_in[2];
  const float2* mv = (const float2*)d_in[3];
  const float*  w  = (const float*)d_in[4];

  char* p = (char*)d_ws;
  float2* sX   = (float2*)p; p += (size_t)NAG * sizeof(float2);
  int*    sidx = (int*)p;    p += (size_t)NAG * sizeof(int);
  float4* sMP  = (float4*)p; p += (size_t)NK * sizeof(float4);
  float*  sLW  = (float*)p;  p += (size_t)NK * sizeof(float);
  float2* cbK  = (float2*)p; p += (size_t)NCK * sizeof(float2);
  float2* cbG  = (float2*)p; p += (size_t)NCG * sizeof(float2);
  float2* bbA  = (float2*)p; p += (size_t)NBLK * sizeof(float2);
  p = (char*)(((uintptr_t)p + 255) & ~(uintptr_t)255);
  float4* pK   = (float4*)p; p += (size_t)NCK * NAG * sizeof(float4);
  float4* pG   = (float4*)p;

  wm_sort_kernel<<<1, 1024, 0, stream>>>(t, X, m0, mv, w, sX, sidx, sMP, sLW, cbK, cbG, bbA);
  dim3 grid(NBLK, NCK + NCG);   // 8 x 96 = 768 blocks
  wm_pair_kernel<<<grid, BLOCK, 0, stream>>>(sX, sMP, sLW, cbK, cbG, bbA, pK, pG);
  wm_final_kernel<<<NAG / 64, 64, 0, stream>>>(pK, pG, sidx, (float2*)d_out);
}